// Round 5
// baseline (370.594 us; speedup 1.0000x reference)
//
#include <hip/hip_runtime.h>
#include <stdint.h>

// ---------------------------------------------------------------------------
// WeedLayer. B=8, C=64, H=W=256, PD=32, STRIDE=16 -> n=15, L=225, P=16, E=512,
// HEADS=8, hd=64, fv=4096. X = [patches(128); blocks(1800)] = 1928 rows.
// R5: gather fused into GEMM1 A-staging (per-lane global_load_lds addrs);
//     QKV split-K=1 w/ bias; 128-row tail (Wo+LN+Wm+gelu+Wc) in ONE kernel.
//     8 dispatches total.
// ---------------------------------------------------------------------------

typedef __attribute__((ext_vector_type(8))) short bf16x8;
typedef __attribute__((ext_vector_type(4))) float f32x4;

__device__ __forceinline__ unsigned short f2bf(float x) {
    union { float f; unsigned u; } v; v.f = x;
    unsigned r = v.u + 0x7FFFu + ((v.u >> 16) & 1u);   // RNE
    return (unsigned short)(r >> 16);
}
__device__ __forceinline__ float bf2f(unsigned short x) {
    union { unsigned u; float f; } v; v.u = ((unsigned)x) << 16; return v.f;
}

// async 16B global->LDS; global addr may be fully per-lane, LDS dest is
// wave-uniform base + lane*16.
__device__ __forceinline__ void g2l16(const unsigned short* g, unsigned short* l) {
    __builtin_amdgcn_global_load_lds(
        (const __attribute__((address_space(1))) unsigned int*)g,
        (__attribute__((address_space(3))) unsigned int*)l, 16, 0, 0);
}

// --- K_prep: pool_features | pool_patches | weight f2bf | seg zero ----------
__global__ __launch_bounds__(256) void k_prep(
    const float* __restrict__ f, const float* __restrict__ p,
    const float* __restrict__ Wr, const float* __restrict__ Wqkv,
    const float* __restrict__ Wo, const float* __restrict__ Wm,
    unsigned short* __restrict__ gp, unsigned short* __restrict__ Xb,
    unsigned short* __restrict__ oWr, unsigned short* __restrict__ oWqkv,
    unsigned short* __restrict__ oWo, unsigned short* __restrict__ oWm,
    float* __restrict__ seg)
{
    int blk = blockIdx.x, tid = threadIdx.x;
    if (blk < 8192) {
        if (blk == 0) for (int i = tid; i < 544; i += 256) seg[i] = 0.f;
        unsigned t = blk * 256u + tid;                   // 2,097,152
        unsigned q = t & 127u, r = (t >> 7) & 127u, g = (t >> 14) & 15u, b = t >> 18;
        const float2* f2 = (const float2*)f;
        float s = 0.f;
        unsigned cb = b * 64u + g * 4u;
#pragma unroll
        for (int j = 0; j < 4; ++j)
#pragma unroll
            for (int a = 0; a < 2; ++a) {
                unsigned idx = ((cb + j) * 256u + 2u * r + a) * 256u + 2u * q;
                float2 v = f2[idx >> 1];
                s += v.x + v.y;
            }
        gp[t] = f2bf(s * 0.0625f);
    } else if (blk < 10240) {
        unsigned t = (blk - 8192) * 256u + tid;          // 524,288
        unsigned i = t & 4095u, row = t >> 12;
        unsigned q = i & 15u, r = (i >> 4) & 15u, g = i >> 8;
        const float2* p2 = (const float2*)p;
        float s = 0.f;
        unsigned cb = row * 64u + g * 4u;
#pragma unroll
        for (int j = 0; j < 4; ++j)
#pragma unroll
            for (int a = 0; a < 2; ++a) {
                unsigned idx = ((cb + j) * 32u + 2u * r + a) * 32u + 2u * q;
                float2 v = p2[idx >> 1];
                s += v.x + v.y;
            }
        Xb[(size_t)row * 4096 + i] = f2bf(s * 0.0625f);
    } else {
        int t = (blk - 10240) * 256 + tid;               // 851,968 float4 groups
        const float* src; unsigned short* dst; int i;
        if (t < 524288)      { src = Wr;   dst = oWr;   i = t; }
        else if (t < 720896) { src = Wqkv; dst = oWqkv; i = t - 524288; }
        else if (t < 786432) { src = Wo;   dst = oWo;   i = t - 720896; }
        else                 { src = Wm;   dst = oWm;   i = t - 786432; }
        float4 v = ((const float4*)src)[i];
        ushort4 o;
        o.x = f2bf(v.x); o.y = f2bf(v.y); o.z = f2bf(v.z); o.w = f2bf(v.w);
        ((ushort4*)dst)[i] = o;
    }
}

// --- 128x128-tile bf16 NT GEMM; GATHER mode reads block rows from Gp --------
// A layout (GATHER): rows 0..127 from Xb[128,4096]; rows 128..1927 computed
// crop addresses into Gp(8,16,128,128). apatch is wave-uniform per block.
template<bool GATHER>
__global__ __launch_bounds__(256) void k_gemm128(
    const unsigned short* __restrict__ A, const unsigned short* __restrict__ Gp,
    const unsigned short* __restrict__ Bw,
    const float* __restrict__ bias, float* __restrict__ C,
    int M, int N, int K, int klen)
{
    __shared__ __align__(16) unsigned short As[128 * 32];
    __shared__ __align__(16) unsigned short Bs[128 * 32];
    const int tid = threadIdx.x, w = tid >> 6, lane = tid & 63;
    const int nt = blockIdx.x, mt = blockIdx.y, ks = blockIdx.z;
    const int kbase = ks * klen;
    const int l15 = lane & 15, kq = (lane >> 4) * 8;
    const int wm = (w >> 1) * 64, wn = (w & 1) * 64;
    const int srow0 = w * 32, lrow = lane >> 2, lcol = (lane & 3) * 8;

    // per-c A row bases
    size_t arowbase[2]; bool apatch[2];
#pragma unroll
    for (int c = 0; c < 2; ++c) {
        int r = srow0 + c * 16 + lrow;
        int ga = mt * 128 + r; if (ga > M - 1) ga = M - 1;
        if (GATHER && ga >= 128) {
            int rr = ga - 128;
            int bb = rr / 225, ij = rr - bb * 225;
            int ii = ij / 15, jj = ij - ii * 15;
            arowbase[c] = (size_t)bb * 262144 + ii * 1024 + jj * 8;
            apatch[c] = false;
        } else {
            arowbase[c] = (size_t)ga * K;
            apatch[c] = true;
        }
    }
    const int brow0 = nt * 128;

    f32x4 acc[4][4];
#pragma unroll
    for (int i = 0; i < 4; ++i)
#pragma unroll
        for (int j = 0; j < 4; ++j) acc[i][j] = (f32x4){0.f, 0.f, 0.f, 0.f};

    for (int k0 = 0; k0 < klen; k0 += 32) {
        int kk = kbase + k0;
        int kcol = kk + lcol;
#pragma unroll
        for (int c = 0; c < 2; ++c) {
            const unsigned short* gp_a;
            if (!GATHER || apatch[c]) {
                gp_a = A + arowbase[c] + kcol;
            } else {
                gp_a = Gp + arowbase[c] + ((size_t)(kcol >> 8) << 14)
                     + (((kcol >> 4) & 15) << 7) + (kcol & 15);
            }
            g2l16(gp_a, &As[(srow0 + c * 16) * 32]);
            g2l16(Bw + (size_t)(brow0 + srow0 + c * 16 + lrow) * K + kcol,
                  &Bs[(srow0 + c * 16) * 32]);
        }
        __syncthreads();
        bf16x8 af[4], bf[4];
#pragma unroll
        for (int i = 0; i < 4; ++i) {
            af[i] = *(const bf16x8*)&As[(wm + 16 * i + l15) * 32 + kq];
            bf[i] = *(const bf16x8*)&Bs[(wn + 16 * i + l15) * 32 + kq];
        }
#pragma unroll
        for (int i = 0; i < 4; ++i)
#pragma unroll
            for (int j = 0; j < 4; ++j)
                acc[i][j] = __builtin_amdgcn_mfma_f32_16x16x32_bf16(af[i], bf[j], acc[i][j], 0, 0, 0);
        __syncthreads();
    }
    float* Cp = C + (size_t)ks * M * N;
#pragma unroll
    for (int i = 0; i < 4; ++i) {
        int rowb = mt * 128 + wm + i * 16 + (lane >> 4) * 4;
#pragma unroll
        for (int j = 0; j < 4; ++j) {
            int col = nt * 128 + wn + j * 16 + l15;
            float bv = bias ? bias[col] : 0.f;
#pragma unroll
            for (int r = 0; r < 4; ++r) {
                int row = rowb + r;
                if (row < M) Cp[(size_t)row * N + col] = acc[i][j][r] + bv;
            }
        }
    }
}

// --- nsplit-partial reduce + bias + LayerNorm (wave/row) --------------------
__global__ __launch_bounds__(256) void k_lnred(
    const float* __restrict__ Yp, const float* __restrict__ br,
    const float* __restrict__ gg, const float* __restrict__ bb,
    float* __restrict__ outF, unsigned short* __restrict__ outB,
    int rows, int nsplit)
{
    int wave = threadIdx.x >> 6, lane = threadIdx.x & 63;
    int row = blockIdx.x * 4 + wave;
    if (row >= rows) return;
    size_t base = (size_t)row * 512 + lane * 8;
    float v[8];
    { const float* bp = br + lane * 8;
      float4 a = *(const float4*)bp, b = *(const float4*)(bp + 4);
      v[0]=a.x; v[1]=a.y; v[2]=a.z; v[3]=a.w; v[4]=b.x; v[5]=b.y; v[6]=b.z; v[7]=b.w; }
    for (int s = 0; s < nsplit; ++s) {
        const float* xp = Yp + (size_t)s * rows * 512 + base;
        float4 a = *(const float4*)xp, b = *(const float4*)(xp + 4);
        v[0]+=a.x; v[1]+=a.y; v[2]+=a.z; v[3]+=a.w; v[4]+=b.x; v[5]+=b.y; v[6]+=b.z; v[7]+=b.w;
    }
    float s = 0.f;
#pragma unroll
    for (int i = 0; i < 8; ++i) s += v[i];
#pragma unroll
    for (int m = 32; m; m >>= 1) s += __shfl_xor(s, m, 64);
    float mu = s * (1.f / 512.f);
    float sq = 0.f;
#pragma unroll
    for (int i = 0; i < 8; ++i) { float d = v[i] - mu; sq += d * d; }
#pragma unroll
    for (int m = 32; m; m >>= 1) sq += __shfl_xor(sq, m, 64);
    float rstd = rsqrtf(sq * (1.f / 512.f) + 1e-5f);
    const float* gp = gg + lane * 8;
    const float* bp2 = bb + lane * 8;
    float4 g0 = *(const float4*)gp, g1 = *(const float4*)(gp + 4);
    float4 b0 = *(const float4*)bp2, b1 = *(const float4*)(bp2 + 4);
    float ga[8] = {g0.x,g0.y,g0.z,g0.w,g1.x,g1.y,g1.z,g1.w};
    float ba[8] = {b0.x,b0.y,b0.z,b0.w,b1.x,b1.y,b1.z,b1.w};
    float o[8];
#pragma unroll
    for (int i = 0; i < 8; ++i) o[i] = (v[i] - mu) * rstd * ga[i] + ba[i];
    float* ofp = outF + base;
    float4 w0; w0.x=o[0]; w0.y=o[1]; w0.z=o[2]; w0.w=o[3];
    float4 w1; w1.x=o[4]; w1.y=o[5]; w1.z=o[6]; w1.w=o[7];
    *(float4*)ofp = w0; *(float4*)(ofp + 4) = w1;
    unsigned short* obp = outB + base;
    ushort4 u0, u1;
    u0.x=f2bf(o[0]); u0.y=f2bf(o[1]); u0.z=f2bf(o[2]); u0.w=f2bf(o[3]);
    u1.x=f2bf(o[4]); u1.y=f2bf(o[5]); u1.z=f2bf(o[6]); u1.w=f2bf(o[7]);
    ((ushort4*)obp)[0] = u0; ((ushort4*)obp)[1] = u1;
}

// --- attention: grid (8b, 8h, 4pz), 4 queries/block; QKV fp32 w/ bias -------
__global__ __launch_bounds__(256) void k_attn(
    const float* __restrict__ QKV, unsigned short* __restrict__ attn_bf)
{
    const int b = blockIdx.x, h = blockIdx.y, pz = blockIdx.z;
    __shared__ __align__(16) float qs[4 * 64];
    __shared__ __align__(16) unsigned short Ks[225 * 68];  // padded stride
    __shared__ __align__(16) unsigned short Vs[225 * 64];
    __shared__ float sc[4 * 225];
    const int t = threadIdx.x;

    {   // stage Q (4 rows x 64)
        int p = t >> 6, d = t & 63;
        qs[t] = QKV[(size_t)(b * 16 + pz * 4 + p) * 1536 + h * 64 + d];
    }
    for (int i = t; i < 14400; i += 256) {
        int l = i >> 6, d = i & 63;
        size_t base = (size_t)(128 + b * 225 + l) * 1536 + h * 64 + d;
        Ks[l * 68 + d] = f2bf(QKV[base + 512]);
        Vs[l * 64 + d] = f2bf(QKV[base + 1024]);
    }
    __syncthreads();
    for (int i = t; i < 900; i += 256) {
        int p = i / 225, l = i - p * 225;
        const ushort4* k4 = (const ushort4*)&Ks[l * 68];
        const float4* q4 = (const float4*)&qs[p * 64];
        float s = 0.f;
#pragma unroll
        for (int d = 0; d < 16; ++d) {
            ushort4 kk = k4[d]; float4 qq = q4[d];
            s += bf2f(kk.x) * qq.x + bf2f(kk.y) * qq.y
               + bf2f(kk.z) * qq.z + bf2f(kk.w) * qq.w;
        }
        sc[p * 225 + l] = s * 0.125f;   // 1/sqrt(64)
    }
    __syncthreads();
    const int lane = t & 63, wave = t >> 6;
    {
        float* row = &sc[wave * 225];
        float m = -1e30f;
        for (int l = lane; l < 225; l += 64) m = fmaxf(m, row[l]);
#pragma unroll
        for (int off = 32; off; off >>= 1) m = fmaxf(m, __shfl_xor(m, off, 64));
        float s = 0.f;
        for (int l = lane; l < 225; l += 64) { float e = __expf(row[l] - m); row[l] = e; s += e; }
#pragma unroll
        for (int off = 32; off; off >>= 1) s += __shfl_xor(s, off, 64);
        float inv = 1.f / s;
        for (int l = lane; l < 225; l += 64) row[l] *= inv;
    }
    __syncthreads();
    {
        float o = 0.f;
        const float* scp = &sc[wave * 225];
        for (int l = 0; l < 225; ++l) o += scp[l] * bf2f(Vs[l * 64 + lane]);
        attn_bf[(size_t)(b * 16 + pz * 4 + wave) * 512 + h * 64 + lane] = f2bf(o);
    }
}

// --- tail: Zo=attnb@Wo^T+bo; res=LN(Zo+pe); M1=resb@Wm^T+bm;
//     outs=(gelu(M1)+res)@Wc^T+bc.  8 blocks x 16 rows, everything in-block.
__global__ __launch_bounds__(256) void k_tail(
    const unsigned short* __restrict__ attnb, const unsigned short* __restrict__ Wo_b,
    const float* __restrict__ bo, const float* __restrict__ LNf,
    const float* __restrict__ gg, const float* __restrict__ bb,
    const unsigned short* __restrict__ Wm_b, const float* __restrict__ bm,
    const float* __restrict__ Wc, const float* __restrict__ bc,
    float* __restrict__ outs)
{
    __shared__ __align__(16) unsigned short Abuf[16 * 520];  // padded rows
    __shared__ __align__(16) unsigned short Bs[4][128 * 32];
    __shared__ float Zf[16 * 512];
    __shared__ float part[16][4][2];
    const int tid = threadIdx.x, w = tid >> 6, lane = tid & 63;
    const int l15 = lane & 15, quad = lane >> 4, kq = quad * 8;
    const int r0 = blockIdx.x * 16;

    // stage A = attnb rows r0..r0+15 (1 row = 64 lanes x 16B)
#pragma unroll
    for (int c = 0; c < 4; ++c) {
        int row = c * 4 + w;
        g2l16(attnb + (size_t)(r0 + row) * 512 + lane * 8, &Abuf[row * 520]);
    }

    f32x4 acc[8];
#pragma unroll
    for (int i = 0; i < 8; ++i) acc[i] = (f32x4){0.f, 0.f, 0.f, 0.f};

    // GEMM-Z: wave w owns cols w*128..+127
    for (int k0 = 0; k0 < 512; k0 += 32) {
#pragma unroll
        for (int c = 0; c < 8; ++c) {
            int n = w * 128 + c * 16 + (lane >> 2);
            g2l16(Wo_b + (size_t)n * 512 + k0 + (lane & 3) * 8, &Bs[w][(c * 16) * 32]);
        }
        __syncthreads();
        bf16x8 af = *(const bf16x8*)&Abuf[l15 * 520 + k0 + kq];
#pragma unroll
        for (int i = 0; i < 8; ++i) {
            bf16x8 bf = *(const bf16x8*)&Bs[w][(i * 16 + l15) * 32 + kq];
            acc[i] = __builtin_amdgcn_mfma_f32_16x16x32_bf16(af, bf, acc[i], 0, 0, 0);
        }
        __syncthreads();
    }
    // Zf = acc + bo
#pragma unroll
    for (int i = 0; i < 8; ++i) {
        int col = w * 128 + i * 16 + l15;
        float bv = bo[col];
#pragma unroll
        for (int r = 0; r < 4; ++r)
            Zf[(quad * 4 + r) * 512 + col] = acc[i][r] + bv;
    }
    __syncthreads();

    // LN(Z + pe-residual): wave per row, 4 passes; res fp32 -> Zf, bf16 -> Abuf
    for (int pass = 0; pass < 4; ++pass) {
        int row = pass * 4 + w;
        float v[8];
#pragma unroll
        for (int i = 0; i < 8; ++i)
            v[i] = Zf[row * 512 + lane * 8 + i] + LNf[(size_t)(r0 + row) * 512 + lane * 8 + i];
        float s = 0.f;
#pragma unroll
        for (int i = 0; i < 8; ++i) s += v[i];
#pragma unroll
        for (int m = 32; m; m >>= 1) s += __shfl_xor(s, m, 64);
        float mu = s * (1.f / 512.f);
        float sq = 0.f;
#pragma unroll
        for (int i = 0; i < 8; ++i) { float d = v[i] - mu; sq += d * d; }
#pragma unroll
        for (int m = 32; m; m >>= 1) sq += __shfl_xor(sq, m, 64);
        float rstd = rsqrtf(sq * (1.f / 512.f) + 1e-5f);
#pragma unroll
        for (int i = 0; i < 8; ++i) {
            int col = lane * 8 + i;
            float o = (v[i] - mu) * rstd * gg[col] + bb[col];
            Zf[row * 512 + col] = o;
            Abuf[row * 520 + col] = f2bf(o);
        }
    }
    __syncthreads();

    // GEMM-M1: same structure on resb
#pragma unroll
    for (int i = 0; i < 8; ++i) acc[i] = (f32x4){0.f, 0.f, 0.f, 0.f};
    for (int k0 = 0; k0 < 512; k0 += 32) {
#pragma unroll
        for (int c = 0; c < 8; ++c) {
            int n = w * 128 + c * 16 + (lane >> 2);
            g2l16(Wm_b + (size_t)n * 512 + k0 + (lane & 3) * 8, &Bs[w][(c * 16) * 32]);
        }
        __syncthreads();
        bf16x8 af = *(const bf16x8*)&Abuf[l15 * 520 + k0 + kq];
#pragma unroll
        for (int i = 0; i < 8; ++i) {
            bf16x8 bf = *(const bf16x8*)&Bs[w][(i * 16 + l15) * 32 + kq];
            acc[i] = __builtin_amdgcn_mfma_f32_16x16x32_bf16(af, bf, acc[i], 0, 0, 0);
        }
        __syncthreads();
    }
    // gelu(M1)+res, dot with Wc
    float s0[4] = {0,0,0,0}, s1[4] = {0,0,0,0};
#pragma unroll
    for (int i = 0; i < 8; ++i) {
        int col = w * 128 + i * 16 + l15;
        float wc0 = Wc[col], wc1 = Wc[512 + col], bmv = bm[col];
#pragma unroll
        for (int r = 0; r < 4; ++r) {
            float v = acc[i][r] + bmv;
            float x = 0.5f * v * (1.f + erff(v * 0.70710678118654752f))
                    + Zf[(quad * 4 + r) * 512 + col];
            s0[r] += x * wc0; s1[r] += x * wc1;
        }
    }
#pragma unroll
    for (int off = 8; off; off >>= 1)
#pragma unroll
        for (int r = 0; r < 4; ++r) {
            s0[r] += __shfl_xor(s0[r], off, 16);
            s1[r] += __shfl_xor(s1[r], off, 16);
        }
    if (l15 == 0)
#pragma unroll
        for (int r = 0; r < 4; ++r) {
            part[quad * 4 + r][w][0] = s0[r];
            part[quad * 4 + r][w][1] = s1[r];
        }
    __syncthreads();
    if (tid < 32) {
        int row = tid >> 1, c = tid & 1;
        float s = part[row][0][c] + part[row][1][c] + part[row][2][c] + part[row][3][c];
        outs[(r0 + row) * 2 + c] = s + bc[c];
    }
}

// --- segment histogram, per-wave LDS accumulators ---------------------------
__global__ __launch_bounds__(256) void k_hist(
    const int* __restrict__ masks, const float* __restrict__ probs,
    float* __restrict__ sums, float* __restrict__ cnt)
{
    __shared__ float ls[4][68];
    int t = threadIdx.x, wave = t >> 6;
    for (int i = t; i < 272; i += 256) ((float*)ls)[i] = 0.f;
    __syncthreads();
    int b = blockIdx.x >> 6, chunk = blockIdx.x & 63;
    int base = chunk * 1024;
    for (int it = 0; it < 4; ++it) {
        int px = base + it * 256 + t;
        int lab = masks[b * 65536 + px];
        atomicAdd(&ls[wave][lab * 3 + 0], probs[(size_t)(b * 3 + 0) * 65536 + px]);
        atomicAdd(&ls[wave][lab * 3 + 1], probs[(size_t)(b * 3 + 1) * 65536 + px]);
        atomicAdd(&ls[wave][lab * 3 + 2], probs[(size_t)(b * 3 + 2) * 65536 + px]);
        atomicAdd(&ls[wave][51 + lab], 1.f);
    }
    __syncthreads();
    if (t < 68) {
        float v = ls[0][t] + ls[1][t] + ls[2][t] + ls[3][t];
        if (t < 51) atomicAdd(&sums[b * 51 + t], v);
        else        atomicAdd(&cnt[b * 17 + t - 51], v);
    }
}

// --- final gather, newv table computed per-block ----------------------------
__global__ __launch_bounds__(256) void k_out(
    const int* __restrict__ masks, const float* __restrict__ probs,
    const float* __restrict__ seg, const float* __restrict__ outs,
    float* __restrict__ out)
{
    __shared__ float nv[17 * 3];
    int tid = threadIdx.x;
    int b = blockIdx.x >> 8;
    if (tid < 17) {
        int lab = tid;
        if (lab == 0) { nv[0] = 0.f; nv[1] = 0.f; nv[2] = 0.f; }
        else {
            float c  = fmaxf(seg[408 + b * 17 + lab], 1.f);
            float m0 = seg[(b * 17 + lab) * 3 + 0] / c + 1e-6f;
            float m1 = seg[(b * 17 + lab) * 3 + 1] / c + 1e-6f;
            float m2 = seg[(b * 17 + lab) * 3 + 2] / c + 1e-6f;
            int p = lab - 1;
            float o0 = outs[(b * 16 + p) * 2 + 0], o1 = outs[(b * 16 + p) * 2 + 1];
            nv[lab * 3 + 0] = m0 / (0.5f * (m1 + m2)) * (0.5f * (o0 + o1));
            nv[lab * 3 + 1] = o0;
            nv[lab * 3 + 2] = o1;
        }
    }
    __syncthreads();
    int px = (blockIdx.x & 255) * 256 + tid;
    int gl = b * 65536 + px;
    int lab = masks[gl];
    if (lab > 0) {
        out[(size_t)(b*3+0)*65536 + px] = nv[lab*3+0];
        out[(size_t)(b*3+1)*65536 + px] = nv[lab*3+1];
        out[(size_t)(b*3+2)*65536 + px] = nv[lab*3+2];
    } else {
        out[(size_t)(b*3+0)*65536 + px] = probs[(size_t)(b*3+0)*65536 + px];
        out[(size_t)(b*3+1)*65536 + px] = probs[(size_t)(b*3+1)*65536 + px];
        out[(size_t)(b*3+2)*65536 + px] = probs[(size_t)(b*3+2)*65536 + px];
    }
}

// ---------------------------------------------------------------------------
extern "C" void kernel_launch(void* const* d_in, const int* in_sizes, int n_in,
                              void* d_out, int out_size, void* d_ws, size_t ws_size,
                              hipStream_t stream)
{
    const float* features = (const float*)d_in[0];
    const float* probs    = (const float*)d_in[1];
    const float* patches  = (const float*)d_in[2];
    const int*   masks    = (const int*)d_in[3];
    const float* ln_g     = (const float*)d_in[4];
    const float* ln_b     = (const float*)d_in[5];
    const float* Wr       = (const float*)d_in[6];
    const float* br       = (const float*)d_in[7];
    const float* Wqkv     = (const float*)d_in[8];
    const float* bqkv     = (const float*)d_in[9];
    const float* Wo       = (const float*)d_in[10];
    const float* bo       = (const float*)d_in[11];
    const float* Wm       = (const float*)d_in[12];
    const float* bm       = (const float*)d_in[13];
    const float* Wc       = (const float*)d_in[14];
    const float* bc       = (const float*)d_in[15];
    float* out = (float*)d_out;

    char* w = (char*)d_ws;
    size_t off = 0;
    auto alloc = [&](size_t bytes) -> char* {
        char* p = w + off;
        off += (bytes + 255) & ~(size_t)255;
        return p;
    };
    unsigned short* Gp     = (unsigned short*)alloc((size_t)2097152 * 2);
    unsigned short* Xb     = (unsigned short*)alloc((size_t)128 * 4096 * 2);
    unsigned short* Wr_b   = (unsigned short*)alloc((size_t)2097152 * 2);
    unsigned short* Wqkv_b = (unsigned short*)alloc((size_t)786432 * 2);
    unsigned short* Wo_b   = (unsigned short*)alloc((size_t)262144 * 2);
    unsigned short* Wm_b   = (unsigned short*)alloc((size_t)262144 * 2);
    float* Yp   = (float*)alloc((size_t)8 * 1928 * 512 * 4);   // split-K=8
    float* LNf  = (float*)alloc((size_t)1928 * 512 * 4);
    unsigned short* LNb = (unsigned short*)alloc((size_t)1928 * 512 * 2);
    float* QKV  = (float*)alloc((size_t)1928 * 1536 * 4);
    unsigned short* attnb = (unsigned short*)alloc((size_t)65536 * 2);
    float* outsB = (float*)alloc((size_t)256 * 4);
    float* seg   = (float*)alloc((size_t)544 * 4);   // 408 sums + 136 cnt

    // 1: pools + weight cvt + seg zero
    k_prep<<<13568, 256, 0, stream>>>(features, patches, Wr, Wqkv, Wo, Wm,
                                      Gp, Xb, Wr_b, Wqkv_b, Wo_b, Wm_b, seg);
    // 2: segment stats (independent of GEMM chain)
    k_hist<<<512, 256, 0, stream>>>(masks, probs, seg, seg + 408);
    // 3: GEMM1 split-K=8 with fused block-gather (512 blocks)
    k_gemm128<true><<<dim3(4, 16, 8), 256, 0, stream>>>(
        Xb, Gp, Wr_b, nullptr, Yp, 1928, 512, 4096, 512);
    // 4: reduce + br + LN1
    k_lnred<<<482, 256, 0, stream>>>(Yp, br, ln_g, ln_b, LNf, LNb, 1928, 8);
    // 5: QKV = LNb @ Wqkv^T + bqkv (192 blocks)
    k_gemm128<false><<<dim3(12, 16, 1), 256, 0, stream>>>(
        LNb, nullptr, Wqkv_b, bqkv, QKV, 1928, 1536, 512, 512);
    // 6: attention (256 blocks)
    k_attn<<<dim3(8, 8, 4), 256, 0, stream>>>(QKV, attnb);
    // 7: fused tail (Wo + LN + Wm + gelu + Wc)
    k_tail<<<8, 256, 0, stream>>>(attnb, Wo_b, bo, LNf, ln_g, ln_b,
                                  Wm_b, bm, Wc, bc, outsB);
    // 8: final gather
    k_out<<<2048, 256, 0, stream>>>(masks, probs, seg, outsB, out);
}

// Round 6
// 363.028 us; speedup vs baseline: 1.0208x; 1.0208x over previous
//
#include <hip/hip_runtime.h>
#include <stdint.h>

// ---------------------------------------------------------------------------
// WeedLayer. B=8, C=64, H=W=256, PD=32, STRIDE=16 -> n=15, L=225, P=16, E=512,
// HEADS=8, hd=64, fv=4096. X = [patches(128); blocks(1800)] = 1928 rows.
// R6: k_tail BK=64 (half the barrier drains); QKV stored bf16; float4 feature
//     pooling; LNf only for pe rows. 8 dispatches.
// ---------------------------------------------------------------------------

typedef __attribute__((ext_vector_type(8))) short bf16x8;
typedef __attribute__((ext_vector_type(4))) float f32x4;

__device__ __forceinline__ unsigned short f2bf(float x) {
    union { float f; unsigned u; } v; v.f = x;
    unsigned r = v.u + 0x7FFFu + ((v.u >> 16) & 1u);   // RNE
    return (unsigned short)(r >> 16);
}
__device__ __forceinline__ float bf2f(unsigned short x) {
    union { unsigned u; float f; } v; v.u = ((unsigned)x) << 16; return v.f;
}

__device__ __forceinline__ void g2l16(const unsigned short* g, unsigned short* l) {
    __builtin_amdgcn_global_load_lds(
        (const __attribute__((address_space(1))) unsigned int*)g,
        (__attribute__((address_space(3))) unsigned int*)l, 16, 0, 0);
}

// --- K_prep: pool_features(float4) | pool_patches | weight f2bf | seg zero --
__global__ __launch_bounds__(256) void k_prep(
    const float* __restrict__ f, const float* __restrict__ p,
    const float* __restrict__ Wr, const float* __restrict__ Wqkv,
    const float* __restrict__ Wo, const float* __restrict__ Wm,
    unsigned short* __restrict__ gp, unsigned short* __restrict__ Xb,
    unsigned short* __restrict__ oWr, unsigned short* __restrict__ oWqkv,
    unsigned short* __restrict__ oWo, unsigned short* __restrict__ oWm,
    float* __restrict__ seg)
{
    int blk = blockIdx.x, tid = threadIdx.x;
    if (blk < 4096) {
        if (blk == 0) for (int i = tid; i < 544; i += 256) seg[i] = 0.f;
        unsigned t = blk * 256u + tid;                   // 1,048,576 out-pairs
        unsigned q2 = t & 63u, r = (t >> 6) & 127u, g = (t >> 13) & 15u, b = t >> 17;
        const float4* f4 = (const float4*)f;
        float s0 = 0.f, s1 = 0.f;
        unsigned cb = b * 64u + g * 4u;
#pragma unroll
        for (int j = 0; j < 4; ++j)
#pragma unroll
            for (int a = 0; a < 2; ++a) {
                float4 v = f4[((cb + j) * 256u + 2u * r + a) * 64u + q2];
                s0 += v.x + v.y; s1 += v.z + v.w;
            }
        ushort2 o; o.x = f2bf(s0 * 0.0625f); o.y = f2bf(s1 * 0.0625f);
        ((ushort2*)gp)[((b * 16u + g) * 128u + r) * 64u + q2] = o;
    } else if (blk < 6144) {
        unsigned t = (blk - 4096) * 256u + tid;          // 524,288
        unsigned i = t & 4095u, row = t >> 12;
        unsigned q = i & 15u, r = (i >> 4) & 15u, g = i >> 8;
        const float2* p2 = (const float2*)p;
        float s = 0.f;
        unsigned cb = row * 64u + g * 4u;
#pragma unroll
        for (int j = 0; j < 4; ++j)
#pragma unroll
            for (int a = 0; a < 2; ++a) {
                unsigned idx = ((cb + j) * 32u + 2u * r + a) * 32u + 2u * q;
                float2 v = p2[idx >> 1];
                s += v.x + v.y;
            }
        Xb[(size_t)row * 4096 + i] = f2bf(s * 0.0625f);
    } else {
        int t = (blk - 6144) * 256 + tid;                // 851,968 float4 groups
        const float* src; unsigned short* dst; int i;
        if (t < 524288)      { src = Wr;   dst = oWr;   i = t; }
        else if (t < 720896) { src = Wqkv; dst = oWqkv; i = t - 524288; }
        else if (t < 786432) { src = Wo;   dst = oWo;   i = t - 720896; }
        else                 { src = Wm;   dst = oWm;   i = t - 786432; }
        float4 v = ((const float4*)src)[i];
        ushort4 o;
        o.x = f2bf(v.x); o.y = f2bf(v.y); o.z = f2bf(v.z); o.w = f2bf(v.w);
        ((ushort4*)dst)[i] = o;
    }
}

// --- 128x128-tile bf16 NT GEMM; GATHER reads block rows from Gp; optional
//     bf16 output ---------------------------------------------------------
template<bool GATHER, bool BF16OUT>
__global__ __launch_bounds__(256) void k_gemm128(
    const unsigned short* __restrict__ A, const unsigned short* __restrict__ Gp,
    const unsigned short* __restrict__ Bw,
    const float* __restrict__ bias, float* __restrict__ C,
    unsigned short* __restrict__ Cb,
    int M, int N, int K, int klen)
{
    __shared__ __align__(16) unsigned short As[128 * 32];
    __shared__ __align__(16) unsigned short Bs[128 * 32];
    const int tid = threadIdx.x, w = tid >> 6, lane = tid & 63;
    const int nt = blockIdx.x, mt = blockIdx.y, ks = blockIdx.z;
    const int kbase = ks * klen;
    const int l15 = lane & 15, kq = (lane >> 4) * 8;
    const int wm = (w >> 1) * 64, wn = (w & 1) * 64;
    const int srow0 = w * 32, lrow = lane >> 2, lcol = (lane & 3) * 8;

    size_t arowbase[2]; bool apatch[2];
#pragma unroll
    for (int c = 0; c < 2; ++c) {
        int r = srow0 + c * 16 + lrow;
        int ga = mt * 128 + r; if (ga > M - 1) ga = M - 1;
        if (GATHER && ga >= 128) {
            int rr = ga - 128;
            int bb = rr / 225, ij = rr - bb * 225;
            int ii = ij / 15, jj = ij - ii * 15;
            arowbase[c] = (size_t)bb * 262144 + ii * 1024 + jj * 8;
            apatch[c] = false;
        } else {
            arowbase[c] = (size_t)ga * K;
            apatch[c] = true;
        }
    }
    const int brow0 = nt * 128;

    f32x4 acc[4][4];
#pragma unroll
    for (int i = 0; i < 4; ++i)
#pragma unroll
        for (int j = 0; j < 4; ++j) acc[i][j] = (f32x4){0.f, 0.f, 0.f, 0.f};

    for (int k0 = 0; k0 < klen; k0 += 32) {
        int kcol = kbase + k0 + lcol;
#pragma unroll
        for (int c = 0; c < 2; ++c) {
            const unsigned short* gp_a;
            if (!GATHER || apatch[c]) {
                gp_a = A + arowbase[c] + kcol;
            } else {
                gp_a = Gp + arowbase[c] + ((size_t)(kcol >> 8) << 14)
                     + (((kcol >> 4) & 15) << 7) + (kcol & 15);
            }
            g2l16(gp_a, &As[(srow0 + c * 16) * 32]);
            g2l16(Bw + (size_t)(brow0 + srow0 + c * 16 + lrow) * K + kcol,
                  &Bs[(srow0 + c * 16) * 32]);
        }
        __syncthreads();
        bf16x8 af[4], bf[4];
#pragma unroll
        for (int i = 0; i < 4; ++i) {
            af[i] = *(const bf16x8*)&As[(wm + 16 * i + l15) * 32 + kq];
            bf[i] = *(const bf16x8*)&Bs[(wn + 16 * i + l15) * 32 + kq];
        }
#pragma unroll
        for (int i = 0; i < 4; ++i)
#pragma unroll
            for (int j = 0; j < 4; ++j)
                acc[i][j] = __builtin_amdgcn_mfma_f32_16x16x32_bf16(af[i], bf[j], acc[i][j], 0, 0, 0);
        __syncthreads();
    }
    float* Cp = C + (size_t)ks * M * N;
#pragma unroll
    for (int i = 0; i < 4; ++i) {
        int rowb = mt * 128 + wm + i * 16 + (lane >> 4) * 4;
#pragma unroll
        for (int j = 0; j < 4; ++j) {
            int col = nt * 128 + wn + j * 16 + l15;
            float bv = bias ? bias[col] : 0.f;
#pragma unroll
            for (int r = 0; r < 4; ++r) {
                int row = rowb + r;
                if (row < M) {
                    if (BF16OUT) Cb[(size_t)row * N + col] = f2bf(acc[i][j][r] + bv);
                    else         Cp[(size_t)row * N + col] = acc[i][j][r] + bv;
                }
            }
        }
    }
}

// --- nsplit-partial reduce + bias + LayerNorm (wave/row); fp32 out only for
//     rows < 128 (pe residual) ------------------------------------------------
__global__ __launch_bounds__(256) void k_lnred(
    const float* __restrict__ Yp, const float* __restrict__ br,
    const float* __restrict__ gg, const float* __restrict__ bb,
    float* __restrict__ outF, unsigned short* __restrict__ outB,
    int rows, int nsplit)
{
    int wave = threadIdx.x >> 6, lane = threadIdx.x & 63;
    int row = blockIdx.x * 4 + wave;
    if (row >= rows) return;
    size_t base = (size_t)row * 512 + lane * 8;
    float v[8];
    { const float* bp = br + lane * 8;
      float4 a = *(const float4*)bp, b = *(const float4*)(bp + 4);
      v[0]=a.x; v[1]=a.y; v[2]=a.z; v[3]=a.w; v[4]=b.x; v[5]=b.y; v[6]=b.z; v[7]=b.w; }
    for (int s = 0; s < nsplit; ++s) {
        const float* xp = Yp + (size_t)s * rows * 512 + base;
        float4 a = *(const float4*)xp, b = *(const float4*)(xp + 4);
        v[0]+=a.x; v[1]+=a.y; v[2]+=a.z; v[3]+=a.w; v[4]+=b.x; v[5]+=b.y; v[6]+=b.z; v[7]+=b.w;
    }
    float s = 0.f;
#pragma unroll
    for (int i = 0; i < 8; ++i) s += v[i];
#pragma unroll
    for (int m = 32; m; m >>= 1) s += __shfl_xor(s, m, 64);
    float mu = s * (1.f / 512.f);
    float sq = 0.f;
#pragma unroll
    for (int i = 0; i < 8; ++i) { float d = v[i] - mu; sq += d * d; }
#pragma unroll
    for (int m = 32; m; m >>= 1) sq += __shfl_xor(sq, m, 64);
    float rstd = rsqrtf(sq * (1.f / 512.f) + 1e-5f);
    const float* gp = gg + lane * 8;
    const float* bp2 = bb + lane * 8;
    float4 g0 = *(const float4*)gp, g1 = *(const float4*)(gp + 4);
    float4 b0 = *(const float4*)bp2, b1 = *(const float4*)(bp2 + 4);
    float ga[8] = {g0.x,g0.y,g0.z,g0.w,g1.x,g1.y,g1.z,g1.w};
    float ba[8] = {b0.x,b0.y,b0.z,b0.w,b1.x,b1.y,b1.z,b1.w};
    float o[8];
#pragma unroll
    for (int i = 0; i < 8; ++i) o[i] = (v[i] - mu) * rstd * ga[i] + ba[i];
    if (row < 128) {
        float* ofp = outF + base;
        float4 w0; w0.x=o[0]; w0.y=o[1]; w0.z=o[2]; w0.w=o[3];
        float4 w1; w1.x=o[4]; w1.y=o[5]; w1.z=o[6]; w1.w=o[7];
        *(float4*)ofp = w0; *(float4*)(ofp + 4) = w1;
    }
    unsigned short* obp = outB + base;
    ushort4 u0, u1;
    u0.x=f2bf(o[0]); u0.y=f2bf(o[1]); u0.z=f2bf(o[2]); u0.w=f2bf(o[3]);
    u1.x=f2bf(o[4]); u1.y=f2bf(o[5]); u1.z=f2bf(o[6]); u1.w=f2bf(o[7]);
    ((ushort4*)obp)[0] = u0; ((ushort4*)obp)[1] = u1;
}

// --- attention: grid (8b, 8h, 4pz); QKV bf16 [1928 x 1536] ------------------
__global__ __launch_bounds__(256) void k_attn(
    const unsigned short* __restrict__ QKVb, unsigned short* __restrict__ attn_bf)
{
    const int b = blockIdx.x, h = blockIdx.y, pz = blockIdx.z;
    __shared__ __align__(16) float qs[4 * 64];
    __shared__ __align__(16) unsigned short Ks[225 * 68];  // padded stride
    __shared__ __align__(16) unsigned short Vs[225 * 64];
    __shared__ float sc[4 * 225];
    const int t = threadIdx.x;

    {   // stage Q (4 rows x 64)
        int p = t >> 6, d = t & 63;
        qs[t] = bf2f(QKVb[(size_t)(b * 16 + pz * 4 + p) * 1536 + h * 64 + d]);
    }
    for (int i = t; i < 1800; i += 256) {              // 8 shorts per item
        int l = i >> 3, d8 = (i & 7) * 8;
        size_t base = (size_t)(128 + b * 225 + l) * 1536 + h * 64 + d8;
        uint4 kk4 = *(const uint4*)(QKVb + base + 512);
        *(uint2*)&Ks[l * 68 + d8]     = make_uint2(kk4.x, kk4.y);
        *(uint2*)&Ks[l * 68 + d8 + 4] = make_uint2(kk4.z, kk4.w);
        *(uint4*)&Vs[l * 64 + d8] = *(const uint4*)(QKVb + base + 1024);
    }
    __syncthreads();
    for (int i = t; i < 900; i += 256) {
        int p = i / 225, l = i - p * 225;
        const ushort4* k4 = (const ushort4*)&Ks[l * 68];
        const float4* q4 = (const float4*)&qs[p * 64];
        float s = 0.f;
#pragma unroll
        for (int d = 0; d < 16; ++d) {
            ushort4 kk = k4[d]; float4 qq = q4[d];
            s += bf2f(kk.x) * qq.x + bf2f(kk.y) * qq.y
               + bf2f(kk.z) * qq.z + bf2f(kk.w) * qq.w;
        }
        sc[p * 225 + l] = s * 0.125f;   // 1/sqrt(64)
    }
    __syncthreads();
    const int lane = t & 63, wave = t >> 6;
    {
        float* row = &sc[wave * 225];
        float m = -1e30f;
        for (int l = lane; l < 225; l += 64) m = fmaxf(m, row[l]);
#pragma unroll
        for (int off = 32; off; off >>= 1) m = fmaxf(m, __shfl_xor(m, off, 64));
        float s = 0.f;
        for (int l = lane; l < 225; l += 64) { float e = __expf(row[l] - m); row[l] = e; s += e; }
#pragma unroll
        for (int off = 32; off; off >>= 1) s += __shfl_xor(s, off, 64);
        float inv = 1.f / s;
        for (int l = lane; l < 225; l += 64) row[l] *= inv;
    }
    __syncthreads();
    {
        float o = 0.f;
        const float* scp = &sc[wave * 225];
        for (int l = 0; l < 225; ++l) o += scp[l] * bf2f(Vs[l * 64 + lane]);
        attn_bf[(size_t)(b * 16 + pz * 4 + wave) * 512 + h * 64 + lane] = f2bf(o);
    }
}

// --- tail: Zo=attnb@Wo^T+bo; res=LN(Zo+pe); M1=res@Wm^T+bm;
//     outs=(gelu(M1)+res)@Wc^T+bc.  8 blocks x 16 rows; BK=64. --------------
__global__ __launch_bounds__(256) void k_tail(
    const unsigned short* __restrict__ attnb, const unsigned short* __restrict__ Wo_b,
    const float* __restrict__ bo, const float* __restrict__ LNf,
    const float* __restrict__ gg, const float* __restrict__ bb,
    const unsigned short* __restrict__ Wm_b, const float* __restrict__ bm,
    const float* __restrict__ Wc, const float* __restrict__ bc,
    float* __restrict__ outs)
{
    __shared__ __align__(16) unsigned short Abuf[16 * 520];
    __shared__ __align__(16) unsigned short Bs[4][128 * 64];   // BK=64
    __shared__ float Zf[16 * 512];
    __shared__ float part[16][4][2];
    const int tid = threadIdx.x, w = tid >> 6, lane = tid & 63;
    const int l15 = lane & 15, quad = lane >> 4, kq = quad * 8;
    const int r0 = blockIdx.x * 16;

#pragma unroll
    for (int c = 0; c < 4; ++c) {
        int row = c * 4 + w;
        g2l16(attnb + (size_t)(r0 + row) * 512 + lane * 8, &Abuf[row * 520]);
    }

    f32x4 acc[8];
#pragma unroll
    for (int i = 0; i < 8; ++i) acc[i] = (f32x4){0.f, 0.f, 0.f, 0.f};

    // GEMM-Z: wave w owns cols w*128..+127, BK=64 (8 steps)
    for (int k0 = 0; k0 < 512; k0 += 64) {
#pragma unroll
        for (int c = 0; c < 16; ++c) {
            int n = w * 128 + c * 8 + (lane >> 3);
            g2l16(Wo_b + (size_t)n * 512 + k0 + (lane & 7) * 8, &Bs[w][c * 512]);
        }
        __syncthreads();
        bf16x8 af0 = *(const bf16x8*)&Abuf[l15 * 520 + k0 + kq];
        bf16x8 af1 = *(const bf16x8*)&Abuf[l15 * 520 + k0 + 32 + kq];
#pragma unroll
        for (int i = 0; i < 8; ++i) {
            bf16x8 b0 = *(const bf16x8*)&Bs[w][(i * 16 + l15) * 64 + kq];
            bf16x8 b1 = *(const bf16x8*)&Bs[w][(i * 16 + l15) * 64 + 32 + kq];
            acc[i] = __builtin_amdgcn_mfma_f32_16x16x32_bf16(af0, b0, acc[i], 0, 0, 0);
            acc[i] = __builtin_amdgcn_mfma_f32_16x16x32_bf16(af1, b1, acc[i], 0, 0, 0);
        }
        __syncthreads();
    }
#pragma unroll
    for (int i = 0; i < 8; ++i) {
        int col = w * 128 + i * 16 + l15;
        float bv = bo[col];
#pragma unroll
        for (int r = 0; r < 4; ++r)
            Zf[(quad * 4 + r) * 512 + col] = acc[i][r] + bv;
    }
    __syncthreads();

    // LN(Z + pe): wave per row, 4 passes
    for (int pass = 0; pass < 4; ++pass) {
        int row = pass * 4 + w;
        float v[8];
#pragma unroll
        for (int i = 0; i < 8; ++i)
            v[i] = Zf[row * 512 + lane * 8 + i] + LNf[(size_t)(r0 + row) * 512 + lane * 8 + i];
        float s = 0.f;
#pragma unroll
        for (int i = 0; i < 8; ++i) s += v[i];
#pragma unroll
        for (int m = 32; m; m >>= 1) s += __shfl_xor(s, m, 64);
        float mu = s * (1.f / 512.f);
        float sq = 0.f;
#pragma unroll
        for (int i = 0; i < 8; ++i) { float d = v[i] - mu; sq += d * d; }
#pragma unroll
        for (int m = 32; m; m >>= 1) sq += __shfl_xor(sq, m, 64);
        float rstd = rsqrtf(sq * (1.f / 512.f) + 1e-5f);
#pragma unroll
        for (int i = 0; i < 8; ++i) {
            int col = lane * 8 + i;
            float o = (v[i] - mu) * rstd * gg[col] + bb[col];
            Zf[row * 512 + col] = o;
            Abuf[row * 520 + col] = f2bf(o);
        }
    }
    __syncthreads();

    // GEMM-M1
#pragma unroll
    for (int i = 0; i < 8; ++i) acc[i] = (f32x4){0.f, 0.f, 0.f, 0.f};
    for (int k0 = 0; k0 < 512; k0 += 64) {
#pragma unroll
        for (int c = 0; c < 16; ++c) {
            int n = w * 128 + c * 8 + (lane >> 3);
            g2l16(Wm_b + (size_t)n * 512 + k0 + (lane & 7) * 8, &Bs[w][c * 512]);
        }
        __syncthreads();
        bf16x8 af0 = *(const bf16x8*)&Abuf[l15 * 520 + k0 + kq];
        bf16x8 af1 = *(const bf16x8*)&Abuf[l15 * 520 + k0 + 32 + kq];
#pragma unroll
        for (int i = 0; i < 8; ++i) {
            bf16x8 b0 = *(const bf16x8*)&Bs[w][(i * 16 + l15) * 64 + kq];
            bf16x8 b1 = *(const bf16x8*)&Bs[w][(i * 16 + l15) * 64 + 32 + kq];
            acc[i] = __builtin_amdgcn_mfma_f32_16x16x32_bf16(af0, b0, acc[i], 0, 0, 0);
            acc[i] = __builtin_amdgcn_mfma_f32_16x16x32_bf16(af1, b1, acc[i], 0, 0, 0);
        }
        __syncthreads();
    }
    float s0[4] = {0,0,0,0}, s1[4] = {0,0,0,0};
#pragma unroll
    for (int i = 0; i < 8; ++i) {
        int col = w * 128 + i * 16 + l15;
        float wc0 = Wc[col], wc1 = Wc[512 + col], bmv = bm[col];
#pragma unroll
        for (int r = 0; r < 4; ++r) {
            float v = acc[i][r] + bmv;
            float x = 0.5f * v * (1.f + erff(v * 0.70710678118654752f))
                    + Zf[(quad * 4 + r) * 512 + col];
            s0[r] += x * wc0; s1[r] += x * wc1;
        }
    }
#pragma unroll
    for (int off = 8; off; off >>= 1)
#pragma unroll
        for (int r = 0; r < 4; ++r) {
            s0[r] += __shfl_xor(s0[r], off, 16);
            s1[r] += __shfl_xor(s1[r], off, 16);
        }
    if (l15 == 0)
#pragma unroll
        for (int r = 0; r < 4; ++r) {
            part[quad * 4 + r][w][0] = s0[r];
            part[quad * 4 + r][w][1] = s1[r];
        }
    __syncthreads();
    if (tid < 32) {
        int row = tid >> 1, c = tid & 1;
        float s = part[row][0][c] + part[row][1][c] + part[row][2][c] + part[row][3][c];
        outs[(r0 + row) * 2 + c] = s + bc[c];
    }
}

// --- segment histogram, per-wave LDS accumulators ---------------------------
__global__ __launch_bounds__(256) void k_hist(
    const int* __restrict__ masks, const float* __restrict__ probs,
    float* __restrict__ sums, float* __restrict__ cnt)
{
    __shared__ float ls[4][68];
    int t = threadIdx.x, wave = t >> 6;
    for (int i = t; i < 272; i += 256) ((float*)ls)[i] = 0.f;
    __syncthreads();
    int b = blockIdx.x >> 6, chunk = blockIdx.x & 63;
    int base = chunk * 1024;
    for (int it = 0; it < 4; ++it) {
        int px = base + it * 256 + t;
        int lab = masks[b * 65536 + px];
        atomicAdd(&ls[wave][lab * 3 + 0], probs[(size_t)(b * 3 + 0) * 65536 + px]);
        atomicAdd(&ls[wave][lab * 3 + 1], probs[(size_t)(b * 3 + 1) * 65536 + px]);
        atomicAdd(&ls[wave][lab * 3 + 2], probs[(size_t)(b * 3 + 2) * 65536 + px]);
        atomicAdd(&ls[wave][51 + lab], 1.f);
    }
    __syncthreads();
    if (t < 68) {
        float v = ls[0][t] + ls[1][t] + ls[2][t] + ls[3][t];
        if (t < 51) atomicAdd(&sums[b * 51 + t], v);
        else        atomicAdd(&cnt[b * 17 + t - 51], v);
    }
}

// --- final gather, newv table computed per-block ----------------------------
__global__ __launch_bounds__(256) void k_out(
    const int* __restrict__ masks, const float* __restrict__ probs,
    const float* __restrict__ seg, const float* __restrict__ outs,
    float* __restrict__ out)
{
    __shared__ float nv[17 * 3];
    int tid = threadIdx.x;
    int b = blockIdx.x >> 8;
    if (tid < 17) {
        int lab = tid;
        if (lab == 0) { nv[0] = 0.f; nv[1] = 0.f; nv[2] = 0.f; }
        else {
            float c  = fmaxf(seg[408 + b * 17 + lab], 1.f);
            float m0 = seg[(b * 17 + lab) * 3 + 0] / c + 1e-6f;
            float m1 = seg[(b * 17 + lab) * 3 + 1] / c + 1e-6f;
            float m2 = seg[(b * 17 + lab) * 3 + 2] / c + 1e-6f;
            int p = lab - 1;
            float o0 = outs[(b * 16 + p) * 2 + 0], o1 = outs[(b * 16 + p) * 2 + 1];
            nv[lab * 3 + 0] = m0 / (0.5f * (m1 + m2)) * (0.5f * (o0 + o1));
            nv[lab * 3 + 1] = o0;
            nv[lab * 3 + 2] = o1;
        }
    }
    __syncthreads();
    int px = (blockIdx.x & 255) * 256 + tid;
    int gl = b * 65536 + px;
    int lab = masks[gl];
    if (lab > 0) {
        out[(size_t)(b*3+0)*65536 + px] = nv[lab*3+0];
        out[(size_t)(b*3+1)*65536 + px] = nv[lab*3+1];
        out[(size_t)(b*3+2)*65536 + px] = nv[lab*3+2];
    } else {
        out[(size_t)(b*3+0)*65536 + px] = probs[(size_t)(b*3+0)*65536 + px];
        out[(size_t)(b*3+1)*65536 + px] = probs[(size_t)(b*3+1)*65536 + px];
        out[(size_t)(b*3+2)*65536 + px] = probs[(size_t)(b*3+2)*65536 + px];
    }
}

// ---------------------------------------------------------------------------
extern "C" void kernel_launch(void* const* d_in, const int* in_sizes, int n_in,
                              void* d_out, int out_size, void* d_ws, size_t ws_size,
                              hipStream_t stream)
{
    const float* features = (const float*)d_in[0];
    const float* probs    = (const float*)d_in[1];
    const float* patches  = (const float*)d_in[2];
    const int*   masks    = (const int*)d_in[3];
    const float* ln_g     = (const float*)d_in[4];
    const float* ln_b     = (const float*)d_in[5];
    const float* Wr       = (const float*)d_in[6];
    const float* br       = (const float*)d_in[7];
    const float* Wqkv     = (const float*)d_in[8];
    const float* bqkv     = (const float*)d_in[9];
    const float* Wo       = (const float*)d_in[10];
    const float* bo       = (const float*)d_in[11];
    const float* Wm       = (const float*)d_in[12];
    const float* bm       = (const float*)d_in[13];
    const float* Wc       = (const float*)d_in[14];
    const float* bc       = (const float*)d_in[15];
    float* out = (float*)d_out;

    char* w = (char*)d_ws;
    size_t off = 0;
    auto alloc = [&](size_t bytes) -> char* {
        char* p = w + off;
        off += (bytes + 255) & ~(size_t)255;
        return p;
    };
    unsigned short* Gp     = (unsigned short*)alloc((size_t)2097152 * 2);
    unsigned short* Xb     = (unsigned short*)alloc((size_t)128 * 4096 * 2);
    unsigned short* Wr_b   = (unsigned short*)alloc((size_t)2097152 * 2);
    unsigned short* Wqkv_b = (unsigned short*)alloc((size_t)786432 * 2);
    unsigned short* Wo_b   = (unsigned short*)alloc((size_t)262144 * 2);
    unsigned short* Wm_b   = (unsigned short*)alloc((size_t)262144 * 2);
    float* Yp   = (float*)alloc((size_t)8 * 1928 * 512 * 4);   // split-K=8
    float* LNf  = (float*)alloc((size_t)128 * 512 * 4);        // pe rows only
    unsigned short* LNb  = (unsigned short*)alloc((size_t)1928 * 512 * 2);
    unsigned short* QKVb = (unsigned short*)alloc((size_t)1928 * 1536 * 2);
    unsigned short* attnb = (unsigned short*)alloc((size_t)65536 * 2);
    float* outsB = (float*)alloc((size_t)256 * 4);
    float* seg   = (float*)alloc((size_t)544 * 4);   // 408 sums + 136 cnt

    // 1: pools + weight cvt + seg zero
    k_prep<<<9472, 256, 0, stream>>>(features, patches, Wr, Wqkv, Wo, Wm,
                                     Gp, Xb, Wr_b, Wqkv_b, Wo_b, Wm_b, seg);
    // 2: segment stats
    k_hist<<<512, 256, 0, stream>>>(masks, probs, seg, seg + 408);
    // 3: GEMM1 split-K=8 with fused gather (512 blocks)
    k_gemm128<true, false><<<dim3(4, 16, 8), 256, 0, stream>>>(
        Xb, Gp, Wr_b, nullptr, Yp, nullptr, 1928, 512, 4096, 512);
    // 4: reduce + br + LN1
    k_lnred<<<482, 256, 0, stream>>>(Yp, br, ln_g, ln_b, LNf, LNb, 1928, 8);
    // 5: QKV = LNb @ Wqkv^T + bqkv, bf16 out (192 blocks)
    k_gemm128<false, true><<<dim3(12, 16, 1), 256, 0, stream>>>(
        LNb, nullptr, Wqkv_b, bqkv, nullptr, QKVb, 1928, 1536, 512, 512);
    // 6: attention (256 blocks)
    k_attn<<<dim3(8, 8, 4), 256, 0, stream>>>(QKVb, attnb);
    // 7: fused tail (Wo + LN + Wm + gelu + Wc), BK=64
    k_tail<<<8, 256, 0, stream>>>(attnb, Wo_b, bo, LNf, ln_g, ln_b,
                                  Wm_b, bm, Wc, bc, outsB);
    // 8: final gather
    k_out<<<2048, 256, 0, stream>>>(masks, probs, seg, outsB, out);
}